// Round 6
// baseline (216.868 us; speedup 1.0000x reference)
//
#include <hip/hip_runtime.h>
#include <hip/hip_bf16.h>

// BoundaryLoss: out = mean(|softmax(pred,axis=1) * (posEDT - negEDT)|)
// B=2, C=4, D=H=W=48. Exact separable squared EDT, bit-matching the JAX ref.
//
// SINGLE kernel, 768 blocks x 192 threads, with a hand-rolled device-scope
// barrier (cooperative launch silently no-runs in this harness - R4):
//  Phase A (blk -> vol*48+d): onehot -> pass1 along w (parallel fwd/bwd L1
//    sweeps on waves 0/1 + square; exact) -> pass2 along h (min-plus,
//    min3-folded) -> store slab to F.
//  Barrier: slot-per-block flag array (initial-value independent: works
//    whether ws is 0xAA-poisoned or zeroed). All 768 blocks are co-resident
//    (28 KB LDS -> 5 blocks/CU x 256 = 1280 >= 768), so no deadlock.
//  Phase B (blk -> ((b,c,h),half)): pos+neg (d,w) slabs -> min-plus along d
//    -> sdf + softmax + |.| -> block reduce -> atomicAdd.
//
// Min-plus algebra: f[j] + (x0+k-j)^2 = (f[j]+dj^2) + 2k*dj + k^2, dj=x0-j.
// All winning-chain values are exact integers < 2^14 in fp32 => bit-exact.

#define SPATIAL 110592   // 48^3
#define NB 2
#define NC 4
#define NLINE 48
#define SLABP 49         // padded LDS row stride
#define NBLK 768
#define MAGIC 0x5CA1AB1Eu

__global__ __launch_bounds__(192) void fused_kernel(const int* __restrict__ target,
                                                    float* __restrict__ F,
                                                    unsigned* __restrict__ bar,
                                                    const float* __restrict__ pred,
                                                    float* __restrict__ out) {
    // LDS carve: phase A uses slabA + aux + tsh; phase B uses slabA + slabB.
    __shared__ float smem[2 * NLINE * SLABP + NLINE * NLINE];  // 7008 f = 28 KB
    float* slabA = smem;                         // 48 x 49
    float* slabB = smem + NLINE * SLABP;         // 48 x 49 (phase B)
    float* aux   = smem + NLINE * SLABP;         // 48 x 48 (phase A, overlays slabB)
    int*   tsh   = (int*)(smem + 2 * NLINE * SLABP);  // 48 x 48 ints

    int blk = blockIdx.x;
    int tid = threadIdx.x;

    // ================= Phase A: WH transform of volume-slab =================
    {
        int vol = blk / NLINE, d = blk - vol * NLINE;   // vol = mask*8 + b*4 + c
        int mask = vol >> 3;
        int b = (vol >> 2) & 1, c = vol & 3;
        if (blk == 0 && tid == 0) *out = 0.0f;          // flushed before barrier

        const int* tslab = target + (b * NLINE + d) * (NLINE * NLINE);
        for (int idx = tid; idx < NLINE * NLINE; idx += 192) tsh[idx] = tslab[idx];
        __syncthreads();

        // ---- pass 1 along w: fwd sweep on wave 0, bwd sweep on wave 1
        if (tid < NLINE) {                    // wave 0: forward
            int h = tid, n = 64;
            for (int w = 0; w < NLINE; ++w) {
                int t = tsh[h * NLINE + w];
                bool set = mask ? (t != c) : (t == c);
                n = set ? 0 : n + 1;
                slabA[h * SLABP + w] = (float)n;
            }
        } else if (tid >= 64 && tid < 64 + NLINE) {   // wave 1: backward
            int h = tid - 64, n = 64;
            for (int w = NLINE - 1; w >= 0; --w) {
                int t = tsh[h * NLINE + w];
                bool set = mask ? (t != c) : (t == c);
                n = set ? 0 : n + 1;
                aux[h * NLINE + w] = (float)n;
            }
        }
        __syncthreads();
        // combine + square (all threads)
        for (int idx = tid; idx < NLINE * NLINE; idx += 192) {
            int h = idx / NLINE, w = idx - h * NLINE;
            float m = fminf(slabA[h * SLABP + w], aux[idx]);
            slabA[h * SLABP + w] = (m >= 48.0f) ? 1e9f : m * m;
        }
        __syncthreads();

        // ---- pass 2 along h: thread -> (column w = tid>>2, 12-chunk over h)
        {
            int w = tid >> 2, cx = (tid & 3) * 12;
            float m[12];
#pragma unroll
            for (int k = 0; k < 12; ++k) m[k] = 1e30f;
            float dj = (float)cx;
            for (int j = 0; j < NLINE; j += 2) {
                float f0 = slabA[j * SLABP + w];
                float f1 = slabA[(j + 1) * SLABP + w];
                float a0 = fmaf(dj, dj, f0);
                float dj1 = dj - 1.0f;
                float a1 = fmaf(dj1, dj1, f1);
#pragma unroll
                for (int k = 0; k < 12; ++k) {
                    float tk = (float)(2 * k);
                    m[k] = fminf(fminf(m[k], fmaf(tk, dj, a0)), fmaf(tk, dj1, a1));
                }
                dj -= 2.0f;
            }
            __syncthreads();           // all reads done before in-place writes
#pragma unroll
            for (int k = 0; k < 12; ++k)
                slabA[(cx + k) * SLABP + w] = m[k] + (float)(k * k);
            __syncthreads();
        }

        // store slab -> F[vol][d][h][w] (coalesced)
        float* fvol = F + (long)vol * SPATIAL + (long)d * (NLINE * NLINE);
        for (int idx = tid; idx < NLINE * NLINE; idx += 192) {
            int h = idx / NLINE, ww = idx - h * NLINE;
            fvol[idx] = slabA[h * SLABP + ww];
        }
    }

    // ================= device-scope barrier (slot per block) ================
    __syncthreads();                   // drains this block's F stores (vmcnt 0)
    if (tid == 0) {
        __threadfence();               // flush XCD L2 -> device-coherent point
        __hip_atomic_store(&bar[blk], MAGIC, __ATOMIC_RELEASE,
                           __HIP_MEMORY_SCOPE_AGENT);
    }
    if (tid < 64) {                    // wave 0 spin-scans all slots
        for (;;) {
            bool ok = true;
            for (int s = tid; s < NBLK; s += 64) {
                unsigned v = __hip_atomic_load(&bar[s], __ATOMIC_ACQUIRE,
                                               __HIP_MEMORY_SCOPE_AGENT);
                ok &= (v == MAGIC);
            }
            if (__all(ok)) break;
            __builtin_amdgcn_s_sleep(2);
        }
    }
    __syncthreads();                   // release all waves into phase B

    // ================= Phase B: D transform + softmax + reduce ==============
    {
        int half = blk & 1;
        int rest = blk >> 1;
        int bc = rest / NLINE, h = rest - bc * NLINE;   // bc = b*4 + c
        int b = bc >> 2, c = bc & 3;

        const float* fp = F + (long)bc * SPATIAL;
        const float* fn = F + (long)(8 + bc) * SPATIAL;
        for (int idx = tid; idx < NLINE * NLINE; idx += 192) {
            int dd = idx / NLINE, ww = idx - dd * NLINE;
            long g = (long)dd * (NLINE * NLINE) + h * NLINE + ww;
            slabA[dd * SLABP + ww] = fp[g];
            slabB[dd * SLABP + ww] = fn[g];
        }
        __syncthreads();

        // min-plus along d (both slabs): thread -> (w = tid>>2, 6-chunk)
        int w = tid >> 2;
        int cx = half * 24 + (tid & 3) * 6;
        float mP[6], mN[6];
#pragma unroll
        for (int k = 0; k < 6; ++k) { mP[k] = 1e30f; mN[k] = 1e30f; }
        float dj = (float)cx;
        for (int j = 0; j < NLINE; j += 2) {
            float fp0 = slabA[j * SLABP + w];
            float fn0 = slabB[j * SLABP + w];
            float fp1 = slabA[(j + 1) * SLABP + w];
            float fn1 = slabB[(j + 1) * SLABP + w];
            float dj1 = dj - 1.0f;
            float aP0 = fmaf(dj, dj, fp0),  aP1 = fmaf(dj1, dj1, fp1);
            float aN0 = fmaf(dj, dj, fn0),  aN1 = fmaf(dj1, dj1, fn1);
#pragma unroll
            for (int k = 0; k < 6; ++k) {
                float tk = (float)(2 * k);
                mP[k] = fminf(fminf(mP[k], fmaf(tk, dj, aP0)), fmaf(tk, dj1, aP1));
                mN[k] = fminf(fminf(mN[k], fmaf(tk, dj, aN0)), fmaf(tk, dj1, aN1));
            }
            dj -= 2.0f;
        }

        // contribution: |softmax_c(pred) * sdf|
        float acc = 0.0f;
        long pbase = (long)b * NC * SPATIAL + (long)h * NLINE + w;
#pragma unroll
        for (int k = 0; k < 6; ++k) {
            int d = cx + k;
            float psq = mP[k] + (float)(k * k);
            float nsq = mN[k] + (float)(k * k);
            float sdf = (psq > 1e8f) ? 0.0f : (sqrtf(psq) - sqrtf(nsq));
            long base = pbase + (long)d * (NLINE * NLINE);
            float p0 = pred[base];
            float p1 = pred[base + SPATIAL];
            float p2 = pred[base + 2 * SPATIAL];
            float p3 = pred[base + 3 * SPATIAL];
            float mx = fmaxf(fmaxf(p0, p1), fmaxf(p2, p3));
            float e0 = __expf(p0 - mx), e1 = __expf(p1 - mx);
            float e2 = __expf(p2 - mx), e3 = __expf(p3 - mx);
            float sum = e0 + e1 + e2 + e3;
            float ec = (c == 0) ? e0 : (c == 1) ? e1 : (c == 2) ? e2 : e3;
            acc += (ec / sum) * fabsf(sdf);
        }

        // block reduce (3 waves)
#pragma unroll
        for (int o = 32; o > 0; o >>= 1) acc += __shfl_down(acc, o, 64);
        __shared__ float wpart[3];
        int lane = tid & 63, wid = tid >> 6;
        if (lane == 0) wpart[wid] = acc;
        __syncthreads();
        if (tid == 0) {
            float v = wpart[0] + wpart[1] + wpart[2];
            atomicAdd(out, v * (1.0f / (float)(NB * NC * SPATIAL)));
        }
    }
}

extern "C" void kernel_launch(void* const* d_in, const int* in_sizes, int n_in,
                              void* d_out, int out_size, void* d_ws, size_t ws_size,
                              hipStream_t stream) {
    const float* pred = (const float*)d_in[0];
    const int* target = (const int*)d_in[1];
    float* out = (float*)d_out;
    float* F = (float*)d_ws;                         // 16 * 110592 floats = 7.08 MB
    unsigned* bar = (unsigned*)(F + 16 * SPATIAL);   // 768 barrier slots after F

    fused_kernel<<<NBLK, 192, 0, stream>>>(target, F, bar, pred, out);
}

// Round 7
// 88.240 us; speedup vs baseline: 2.4577x; 2.4577x over previous
//
#include <hip/hip_runtime.h>
#include <hip/hip_bf16.h>

// BoundaryLoss: out = mean(|softmax(pred,axis=1) * (posEDT - negEDT)|)
// B=2, C=4, D=H=W=48. Exact separable squared EDT, bit-matching the JAX ref.
//
// Two plain kernels. (Grid-wide fusion is dead: R4 cooperative launch silently
// no-ran; R6 hand-rolled spin barrier cost 177us in acquire-load contention.)
//  A (768 blocks): per (vol,d) slab: pass1 along w via per-row __ballot mask +
//    clz/ctz nearest-set-bit distance (O(1)/voxel, exact, no LDS staging) ->
//    pass2 along h (register-blocked min-plus, min3-folded) -> F (float4).
//  B (768 blocks): per (b,c,h,half): float4-stage pos+neg (d,w) slabs ->
//    min-plus along d -> sdf + softmax + |.| -> block reduce -> atomicAdd.
//
// Min-plus algebra: f[j] + (x0+k-j)^2 = (f[j]+dj^2) + 2k*dj + k^2, dj=x0-j.
// All winning-chain values are exact integers < 2^14 in fp32 => bit-exact.
// SLABP=52: rows 16B-aligned (b128 LDS ops legal) and <=2-way bank aliasing
// everywhere (free per m136). R5's SLABP=49 + tsh[h*48+w] had 24-way conflicts
// (SQ_LDS_BANK_CONFLICT=1.07M).

#define SPATIAL 110592   // 48^3
#define NB 2
#define NC 4
#define NLINE 48
#define SLABP 52         // padded LDS row stride, 16B-aligned rows
#define MAGIC_INF 1e9f

__global__ __launch_bounds__(192) void edt_wh_kernel(const int* __restrict__ target,
                                                     float* __restrict__ F,
                                                     float* __restrict__ out) {
    __shared__ float slab[NLINE * SLABP];
    int blk = blockIdx.x;                 // vol*48 + d ; vol = mask*8 + b*4 + c
    int vol = blk / NLINE, d = blk - vol * NLINE;
    int mask = vol >> 3;
    int b = (vol >> 2) & 1, c = vol & 3;
    int tid = threadIdx.x;
    if (blk == 0 && tid == 0) *out = 0.0f;   // visible to kernel B (stream order)

    // ---- pass 1 along w: ballot mask + clz/ctz distance (wave per 16 rows)
    {
        int wid = tid >> 6, lane = tid & 63;        // 3 waves
        const int* tbase = target + ((b * NLINE + d) * NLINE) * NLINE;
#pragma unroll 4
        for (int r = 0; r < 16; ++r) {
            int h = wid * 16 + r;
            int t = (lane < NLINE) ? tbase[h * NLINE + lane] : -1;
            bool inset = mask ? (lane < NLINE && t != c) : (t == c);
            unsigned long long m = __ballot(inset);
            if (lane < NLINE) {
                unsigned long long low = m & (~0ull >> (63 - lane));   // bits 0..lane
                unsigned long long high = m >> lane;                   // bits lane..63
                int left  = low  ? (lane - (63 - __builtin_clzll(low))) : 64;
                int right = high ? __builtin_ctzll(high) : 64;
                int dmin = min(left, right);
                slab[h * SLABP + lane] = (dmin >= NLINE) ? MAGIC_INF
                                                         : (float)(dmin * dmin);
            }
        }
    }
    __syncthreads();

    // ---- pass 2 along h: thread -> (column w = tid>>2, 12-chunk over h)
    {
        int w = tid >> 2, cx = (tid & 3) * 12;
        float m[12];
#pragma unroll
        for (int k = 0; k < 12; ++k) m[k] = 1e30f;
        float dj = (float)cx;
        for (int j = 0; j < NLINE; j += 2) {
            float f0 = slab[j * SLABP + w];
            float f1 = slab[(j + 1) * SLABP + w];
            float a0 = fmaf(dj, dj, f0);
            float dj1 = dj - 1.0f;
            float a1 = fmaf(dj1, dj1, f1);
#pragma unroll
            for (int k = 0; k < 12; ++k) {
                float tk = (float)(2 * k);
                m[k] = fminf(fminf(m[k], fmaf(tk, dj, a0)), fmaf(tk, dj1, a1));
            }
            dj -= 2.0f;
        }
        __syncthreads();               // all reads done before in-place writes
#pragma unroll
        for (int k = 0; k < 12; ++k)
            slab[(cx + k) * SLABP + w] = m[k] + (float)(k * k);
        __syncthreads();
    }

    // store slab -> F[vol][d][h][w], float4 (coalesced 16B/lane)
    float* fvol = F + (long)vol * SPATIAL + (long)d * (NLINE * NLINE);
    for (int q = tid; q < (NLINE * NLINE) / 4; q += 192) {
        int h = q / 12, col4 = (q - h * 12) * 4;
        float4 v = *(const float4*)&slab[h * SLABP + col4];
        *(float4*)&fvol[h * NLINE + col4] = v;     // h*48+col4 == q*4: contiguous
    }
}

__global__ __launch_bounds__(192) void edt_d_reduce_kernel(const float* __restrict__ pred,
                                                           const float* __restrict__ F,
                                                           float* __restrict__ out) {
    __shared__ float slabP[NLINE * SLABP];
    __shared__ float slabN[NLINE * SLABP];
    int blk = blockIdx.x;                 // ((b*4+c)*48 + h)*2 + half
    int half = blk & 1;
    int rest = blk >> 1;
    int bc = rest / NLINE, h = rest - bc * NLINE;
    int b = bc >> 2, c = bc & 3;
    int tid = threadIdx.x;

    // stage slab[d][w] = F[vol][d][h][w] for pos (bc) and neg (8+bc), float4
    const float* fp = F + (long)bc * SPATIAL + (long)h * NLINE;
    const float* fn = F + (long)(8 + bc) * SPATIAL + (long)h * NLINE;
    for (int q = tid; q < (NLINE * NLINE) / 4; q += 192) {
        int dd = q / 12, col4 = (q - dd * 12) * 4;
        long g = (long)dd * (NLINE * NLINE) + col4;
        float4 vp = *(const float4*)&fp[g];
        float4 vn = *(const float4*)&fn[g];
        *(float4*)&slabP[dd * SLABP + col4] = vp;
        *(float4*)&slabN[dd * SLABP + col4] = vn;
    }
    __syncthreads();

    // min-plus along d (both slabs): thread -> (w = tid>>2, 6-chunk)
    int w = tid >> 2;
    int cx = half * 24 + (tid & 3) * 6;
    float mP[6], mN[6];
#pragma unroll
    for (int k = 0; k < 6; ++k) { mP[k] = 1e30f; mN[k] = 1e30f; }
    float dj = (float)cx;
    for (int j = 0; j < NLINE; j += 2) {
        float fp0 = slabP[j * SLABP + w];
        float fn0 = slabN[j * SLABP + w];
        float fp1 = slabP[(j + 1) * SLABP + w];
        float fn1 = slabN[(j + 1) * SLABP + w];
        float dj1 = dj - 1.0f;
        float aP0 = fmaf(dj, dj, fp0),  aP1 = fmaf(dj1, dj1, fp1);
        float aN0 = fmaf(dj, dj, fn0),  aN1 = fmaf(dj1, dj1, fn1);
#pragma unroll
        for (int k = 0; k < 6; ++k) {
            float tk = (float)(2 * k);
            mP[k] = fminf(fminf(mP[k], fmaf(tk, dj, aP0)), fmaf(tk, dj1, aP1));
            mN[k] = fminf(fminf(mN[k], fmaf(tk, dj, aN0)), fmaf(tk, dj1, aN1));
        }
        dj -= 2.0f;
    }

    // contribution: |softmax_c(pred) * sdf|
    float acc = 0.0f;
    long pbase = (long)b * NC * SPATIAL + (long)h * NLINE + w;
#pragma unroll
    for (int k = 0; k < 6; ++k) {
        int d = cx + k;
        float psq = mP[k] + (float)(k * k);
        float nsq = mN[k] + (float)(k * k);
        float sdf = (psq > 1e8f) ? 0.0f : (sqrtf(psq) - sqrtf(nsq));
        long base = pbase + (long)d * (NLINE * NLINE);
        float p0 = pred[base];
        float p1 = pred[base + SPATIAL];
        float p2 = pred[base + 2 * SPATIAL];
        float p3 = pred[base + 3 * SPATIAL];
        float mx = fmaxf(fmaxf(p0, p1), fmaxf(p2, p3));
        float e0 = __expf(p0 - mx), e1 = __expf(p1 - mx);
        float e2 = __expf(p2 - mx), e3 = __expf(p3 - mx);
        float sum = e0 + e1 + e2 + e3;
        float ec = (c == 0) ? e0 : (c == 1) ? e1 : (c == 2) ? e2 : e3;
        acc += (ec / sum) * fabsf(sdf);
    }

    // block reduce (3 waves)
#pragma unroll
    for (int o = 32; o > 0; o >>= 1) acc += __shfl_down(acc, o, 64);
    __shared__ float wpart[3];
    int lane = tid & 63, wid = tid >> 6;
    if (lane == 0) wpart[wid] = acc;
    __syncthreads();
    if (tid == 0) {
        float v = wpart[0] + wpart[1] + wpart[2];
        atomicAdd(out, v * (1.0f / (float)(NB * NC * SPATIAL)));
    }
}

extern "C" void kernel_launch(void* const* d_in, const int* in_sizes, int n_in,
                              void* d_out, int out_size, void* d_ws, size_t ws_size,
                              hipStream_t stream) {
    const float* pred = (const float*)d_in[0];
    const int* target = (const int*)d_in[1];
    float* out = (float*)d_out;
    float* F = (float*)d_ws;   // 16 * 110592 floats = 7.08 MB

    edt_wh_kernel<<<2 * NB * NC * NLINE, 192, 0, stream>>>(target, F, out);        // 768 blocks
    edt_d_reduce_kernel<<<2 * NB * NC * NLINE, 192, 0, stream>>>(pred, F, out);    // 768 blocks
}